// Round 1
// baseline (12910.092 us; speedup 1.0000x reference)
//
#include <hip/hip_runtime.h>
#include <cstdint>

#define T_STEPS 2048
#define HID 256

typedef _Float16 half8 __attribute__((ext_vector_type(8)));
typedef float f32x4 __attribute__((ext_vector_type(4)));

// tanh(x) = 1 - 2/(e^{2x}+1); exp via v_exp_f32, division via v_rcp_f32.
// Handles +-inf gracefully (-> +-1), error ~1e-6.
__device__ __forceinline__ float tanh_fast(float x){
  float t = __expf(2.0f * x);
  float r = __builtin_amdgcn_rcpf(t + 1.0f);
  return __builtin_fmaf(-2.0f, r, 1.0f);
}

// Load 8 consecutive fp32 and round-convert to an MFMA f16x8 fragment.
__device__ __forceinline__ half8 cvt_frag8(const float* __restrict__ p){
  float4 a = *(const float4*)p;
  float4 b = *(const float4*)(p + 4);
  half8 h;
  h[0]=(_Float16)a.x; h[1]=(_Float16)a.y; h[2]=(_Float16)a.z; h[3]=(_Float16)a.w;
  h[4]=(_Float16)b.x; h[5]=(_Float16)b.y; h[6]=(_Float16)b.z; h[7]=(_Float16)b.w;
  return h;
}

// ---------------------------------------------------------------------------
// gemm_xp: per 64-row tile t, compute xp[t] = A[t] @ W^T + (b1 + b2), f16 out.
// Block = 512 threads = 8 waves; wave w -> (mtg = w&1: rows mtg*32..+32,
// ntg = w>>1: cols ntg*64..+64). Per wave: 2 M-tiles x 4 N-tiles of 16x16x32
// MFMA, K=256. Output stored in per-lane MFMA-C fragment order:
// lane chunk = out + t*stride + w*2048 + lane*32, frag f=mt*4+nt at +f*4 f16.
// The recurrence kernel reads the same layout back with plain dwordx4 loads.
// ---------------------------------------------------------------------------
template<bool A_IS_F32>
__global__ __launch_bounds__(512, 2) void gemm_xp(
    const void* __restrict__ Ap, const float* __restrict__ W,
    const float* __restrict__ b1, const float* __restrict__ b2,
    _Float16* __restrict__ out, long out_stride)
{
  const int t   = blockIdx.x;
  const int tid = threadIdx.x;
  const int w = tid >> 6, l = tid & 63;
  const int mtg = w & 1, ntg = w >> 1;
  const int lm = l & 15, lq = l >> 4;

  // B fragments: B[k][n] = W[n][k]; lane (n=lm, kchunk q=lq) reads 8 consecutive k.
  half8 Bf[4][8];
  float bias[4];
  #pragma unroll
  for (int nt = 0; nt < 4; ++nt){
    const int col = ntg*64 + nt*16 + lm;
    #pragma unroll
    for (int kc = 0; kc < 8; ++kc)
      Bf[nt][kc] = cvt_frag8(W + (long)col*HID + kc*32 + lq*8);
    bias[nt] = b1[col] + b2[col];
  }

  // A fragments: A[m=lm][k = lq*8 + j], 8 consecutive k per lane.
  half8 Af[2][8];
  #pragma unroll
  for (int mt = 0; mt < 2; ++mt){
    const long row = (long)t*64 + mtg*32 + mt*16 + lm;
    #pragma unroll
    for (int kc = 0; kc < 8; ++kc){
      const int ko = kc*32 + lq*8;
      if (A_IS_F32) Af[mt][kc] = cvt_frag8((const float*)Ap + row*HID + ko);
      else          Af[mt][kc] = *(const half8*)((const _Float16*)Ap + row*HID + ko);
    }
  }

  f32x4 acc[2][4];
  #pragma unroll
  for (int mt = 0; mt < 2; ++mt)
    #pragma unroll
    for (int nt = 0; nt < 4; ++nt)
      acc[mt][nt] = (f32x4){0.f, 0.f, 0.f, 0.f};

  #pragma unroll
  for (int kc = 0; kc < 8; ++kc)
    #pragma unroll
    for (int mt = 0; mt < 2; ++mt)
      #pragma unroll
      for (int nt = 0; nt < 4; ++nt)
        acc[mt][nt] = __builtin_amdgcn_mfma_f32_16x16x32_f16(
            Af[mt][kc], Bf[nt][kc], acc[mt][nt], 0, 0, 0);

  _Float16* dst = out + (long)t*out_stride + w*2048 + l*32;
  #pragma unroll
  for (int mt = 0; mt < 2; ++mt)
    #pragma unroll
    for (int nt = 0; nt < 4; ++nt){
      f32x4 v = acc[mt][nt];
      const float bb = bias[nt];
      union { _Float16 h[4]; uint64_t u; } p;
      p.h[0] = (_Float16)(v[0] + bb);
      p.h[1] = (_Float16)(v[1] + bb);
      p.h[2] = (_Float16)(v[2] + bb);
      p.h[3] = (_Float16)(v[3] + bb);
      *(uint64_t*)(dst + (mt*4 + nt)*4) = p.u;
    }
}

// ---------------------------------------------------------------------------
// rec_layer: h_t = tanh(xp[t] + h_{t-1} @ Whh^T), single 512-thread block.
// Whh register-resident as B-fragments (128 VGPRs/wave). h double-buffered in
// LDS, row stride 264 f16 (+8 pad -> conflict-free ds_read_b128 A-fragments).
// xp read in the permuted fragment layout written by gemm_xp (4x dwordx4/lane),
// prefetched one step ahead. Optional h_out (f16 row-major, for next layer's
// input GEMM) and out (fp32 row-major final output).
// Barrier after acc-init guarantees all xp[t] loads completed before any
// stores of step t are issued (required: layer-1 xp aliases the low half of
// each 64-KB d_out tile).
// ---------------------------------------------------------------------------
__global__ __launch_bounds__(512, 2) void rec_layer(
    const _Float16* __restrict__ xp, long xp_stride,
    const float* __restrict__ Whh,
    _Float16* __restrict__ h_out, float* __restrict__ out)
{
  __shared__ __align__(16) _Float16 hbuf[2][64][264];
  const int tid = threadIdx.x;
  const int w = tid >> 6, l = tid & 63;
  const int mtg = w & 1, ntg = w >> 1;
  const int lm = l & 15, lq = l >> 4;

  // h_{-1} = 0 (t=0 reads buffer 1)
  for (int i = tid; i < 64*264; i += 512) (&hbuf[1][0][0])[i] = (_Float16)0.f;

  half8 Bf[4][8];
  #pragma unroll
  for (int nt = 0; nt < 4; ++nt){
    const int col = ntg*64 + nt*16 + lm;
    #pragma unroll
    for (int kc = 0; kc < 8; ++kc)
      Bf[nt][kc] = cvt_frag8(Whh + (long)col*HID + kc*32 + lq*8);
  }
  __syncthreads();

  uint4 xpa[4], xpb[4];
  {
    const uint4* s = (const uint4*)(xp + w*2048 + l*32);
    xpa[0]=s[0]; xpa[1]=s[1]; xpa[2]=s[2]; xpa[3]=s[3];
  }

  for (int t = 0; t < T_STEPS; ++t){
    const int pb = (t + 1) & 1, cb = t & 1;

    // acc init = xp[t] (bias already folded in by gemm_xp)
    f32x4 acc[2][4];
    #pragma unroll
    for (int f = 0; f < 8; ++f){
      union { uint32_t u[2]; _Float16 h[4]; } p;
      const uint4 v = xpa[f >> 1];
      p.u[0] = (f & 1) ? v.z : v.x;
      p.u[1] = (f & 1) ? v.w : v.y;
      f32x4 a;
      a[0]=(float)p.h[0]; a[1]=(float)p.h[1]; a[2]=(float)p.h[2]; a[3]=(float)p.h[3];
      acc[f >> 2][f & 3] = a;
    }
    __syncthreads();  // all xp[t] loads consumed before any step-t stores

    if (t + 1 < T_STEPS){
      const uint4* s = (const uint4*)(xp + (long)(t+1)*xp_stride + w*2048 + l*32);
      xpb[0]=s[0]; xpb[1]=s[1]; xpb[2]=s[2]; xpb[3]=s[3];
    }

    #pragma unroll
    for (int kc = 0; kc < 8; ++kc){
      const int ko = kc*32 + lq*8;
      half8 A0 = *(const half8*)&hbuf[pb][mtg*32      + lm][ko];
      half8 A1 = *(const half8*)&hbuf[pb][mtg*32 + 16 + lm][ko];
      #pragma unroll
      for (int nt = 0; nt < 4; ++nt){
        acc[0][nt] = __builtin_amdgcn_mfma_f32_16x16x32_f16(A0, Bf[nt][kc], acc[0][nt], 0,0,0);
        acc[1][nt] = __builtin_amdgcn_mfma_f32_16x16x32_f16(A1, Bf[nt][kc], acc[1][nt], 0,0,0);
      }
    }

    // epilogue: tanh, write h to LDS (f16) and optionally fp32 out
    #pragma unroll
    for (int mt = 0; mt < 2; ++mt)
      #pragma unroll
      for (int nt = 0; nt < 4; ++nt){
        const int col = ntg*64 + nt*16 + lm;
        f32x4 v = acc[mt][nt];
        #pragma unroll
        for (int r = 0; r < 4; ++r){
          const float hv = tanh_fast(v[r]);
          const int row = mtg*32 + mt*16 + lq*4 + r;
          hbuf[cb][row][col] = (_Float16)hv;
          if (out) out[((long)t*64 + row)*HID + col] = hv;
        }
      }
    __syncthreads();

    // linear LDS->global copy of h_t for the next layer's input GEMM
    if (h_out){
      const int row = tid >> 3, c0 = (tid & 7) * 32;
      const uint4* s = (const uint4*)&hbuf[cb][row][c0];
      uint4* d = (uint4*)(h_out + ((long)t*64 + row)*HID + c0);
      d[0]=s[0]; d[1]=s[1]; d[2]=s[2]; d[3]=s[3];
    }

    xpa[0]=xpb[0]; xpa[1]=xpb[1]; xpa[2]=xpb[2]; xpa[3]=xpb[3];
  }
}

// ---------------------------------------------------------------------------
// Buffer plan (no hipMalloc allowed):
//   xp0: f16, tile stride 32 KB, lives in d_out [0, 64 MiB)   (dead after K2)
//   h1 : f16 row-major [T*64][256], lives in d_ws (64 MiB)
//   xp1: f16, tile stride 64 KB = low half of each d_out output tile;
//        consumed at step t strictly before step t's fp32 stores (barrier).
// ---------------------------------------------------------------------------
extern "C" void kernel_launch(void* const* d_in, const int* in_sizes, int n_in,
                              void* d_out, int out_size, void* d_ws, size_t ws_size,
                              hipStream_t stream)
{
  const float* x     = (const float*)d_in[0];
  const float* W_ih0 = (const float*)d_in[1];
  const float* W_hh0 = (const float*)d_in[2];
  const float* b_ih0 = (const float*)d_in[3];
  const float* b_hh0 = (const float*)d_in[4];
  const float* W_ih1 = (const float*)d_in[5];
  const float* W_hh1 = (const float*)d_in[6];
  const float* b_ih1 = (const float*)d_in[7];
  const float* b_hh1 = (const float*)d_in[8];

  _Float16* xp0 = (_Float16*)d_out;
  _Float16* xp1 = (_Float16*)d_out;
  _Float16* h1  = (_Float16*)d_ws;
  float*    out = (float*)d_out;

  gemm_xp<true ><<<T_STEPS, 512, 0, stream>>>(x,  W_ih0, b_ih0, b_hh0, xp0, 16384);
  rec_layer<<<1, 512, 0, stream>>>(xp0, 16384, W_hh0, h1, nullptr);
  gemm_xp<false><<<T_STEPS, 512, 0, stream>>>(h1, W_ih1, b_ih1, b_hh1, xp1, 32768);
  rec_layer<<<1, 512, 0, stream>>>(xp1, 32768, W_hh1, nullptr, out);
}